// Round 5
// baseline (707.398 us; speedup 1.0000x reference)
//
#include <hip/hip_runtime.h>
#include <hip/hip_bf16.h>
#include <float.h>

// Performer FastAttention (FAVOR+), MFMA bf16-split v2.
// q,k,v: [8,12,4096,64] f32; proj: [256,64] f32; out: [8,12,4096,64] f32.
//
//   E = exp(ddk - diagk) accumulated unstabilized (|dd-diag| <~ 30, fp32 safe),
//   ctxE[m][e] = sum_n E*v, Esum, Vsum, stab = max dd.
//   ctxhat = e^{-stab}*ctxE + eps*Vsum ; kshat = e^{-stab}*Esum + eps*N.
//   out = (q'·ctxhat)/(q'·kshat), q' = exp(ddq - diagq - rowmax) + eps.
// All GEMMs: mfma_f32_16x16x32_bf16, 3-term hi/lo split (rel err ~2^-17).

typedef __attribute__((ext_vector_type(8))) short short8v;
typedef __attribute__((ext_vector_type(4))) short short4v;
typedef __attribute__((ext_vector_type(4))) float f32x4;

#define MFMA16(a, b, c) __builtin_amdgcn_mfma_f32_16x16x32_bf16(a, b, c, 0, 0, 0)

namespace {
constexpr int Nn = 4096, Dd = 64, BHn = 96;
constexpr float kNorm = 0.35355339059327379f;  // 64^-0.25
constexpr float kDiagCoef = 0.0625f;           // 0.5 * 64^-0.5
constexpr float kEps = 1e-4f;

constexpr size_t oStab  = 0;                                   // 96 u32
constexpr size_t oEsum  = 512;                                 // 96*256 f32
constexpr size_t oVsum  = oEsum + (size_t)BHn * 256 * 4;       // 96*64 f32
constexpr size_t oKshat = oVsum + (size_t)BHn * 64 * 4;        // 96*256 f32
constexpr size_t oCtxE  = oKshat + (size_t)BHn * 256 * 4;      // 96*256*64 f32
constexpr size_t oCtH   = oCtxE + (size_t)BHn * 256 * 64 * 4;  // 96*64*256 bf16
constexpr size_t oCtL   = oCtH + (size_t)BHn * 64 * 256 * 2;
constexpr size_t oPh    = oCtL + (size_t)BHn * 64 * 256 * 2;   // 256*64 bf16
constexpr size_t oPl    = oPh + (size_t)256 * 64 * 2;
constexpr size_t kZeroBytes = oCtH;  // zero stab..ctxE accumulators
}

static __device__ __forceinline__ unsigned floatKey(float f) {
  unsigned b = __float_as_uint(f);
  return (b & 0x80000000u) ? ~b : (b | 0x80000000u);
}
static __device__ __forceinline__ float keyToFloat(unsigned k) {
  unsigned b = (k & 0x80000000u) ? (k & 0x7fffffffu) : ~k;
  return __uint_as_float(b);
}
static __device__ __forceinline__ short f2bf(float x) {
  union { __hip_bfloat16 h; short s; } u;
  u.h = __float2bfloat16(x);
  return u.s;
}
static __device__ __forceinline__ float bf2f(short s) {
  return __uint_as_float(((unsigned)(unsigned short)s) << 16);
}
static __device__ __forceinline__ void splitbf(float x, short& h, short& l) {
  h = f2bf(x);
  l = f2bf(x - bf2f(h));
}
static __device__ __forceinline__ int sw8(int row, int col) { return col ^ ((row & 7) << 3); }

// ---------------------------------------------------------------------------
// prep: split proj into bf16 hi/lo, linear [m][d] layout (global, L2-hot).
// ---------------------------------------------------------------------------
__global__ void perf_prep(const float* __restrict__ proj, short* __restrict__ Ph,
                          short* __restrict__ Pl) {
  const int i = (blockIdx.x * 256 + threadIdx.x) * 4;  // 16384 elems
  float4 v = *(const float4*)(proj + i);
  float xs[4] = {v.x, v.y, v.z, v.w};
  short4v h, l;
#pragma unroll
  for (int j = 0; j < 4; ++j) {
    short hh, ll;
    splitbf(xs[j], hh, ll);
    h[j] = hh;
    l[j] = ll;
  }
  *(short4v*)(Ph + i) = h;
  *(short4v*)(Pl + i) = l;
}

// ---------------------------------------------------------------------------
// kside: grid (96, 8), block 512 (8 waves), 512 k-rows/block, 8 subs of 64.
// dd = (norm*k)·proj^T via MFMA(a=K frags from global, b=proj frags global);
// E = exp(dd-diag) -> E^T in LDS; ctxE += E^T·v (V^T staged in LDS).
// LDS ~68 KB -> 2 blocks/CU.
// ---------------------------------------------------------------------------
__global__ __launch_bounds__(512, 4) void perf_kside(
    const float* __restrict__ K, const float* __restrict__ V,
    const short* __restrict__ PhG, const short* __restrict__ PlG,
    unsigned* __restrict__ stabKey, float* __restrict__ EsumG,
    float* __restrict__ VsumG, float* __restrict__ ctxEG) {
  const int t = threadIdx.x, bh = blockIdx.x, chunk = blockIdx.y;
  const int w = t >> 6, l = t & 63;
  const int rt = w & 3, msel = w >> 2;
  const int lhi = l >> 4, llo = l & 15;
  const int koff = lhi * 8;

  __shared__ float vtmp[64][68];
  __shared__ short Vh[64][64], Vl[64][64];   // V^T: [e][n]
  __shared__ short Eh[128][64], El[128][64]; // E^T half: [m][n]
  __shared__ float rpartV[8][64];
  __shared__ float wpmax[8];

  float mx = -FLT_MAX, vsum_r = 0.f;
  f32x4 cacc[2][4];
  float es[2][4];
#pragma unroll
  for (int a = 0; a < 2; ++a)
#pragma unroll
    for (int b = 0; b < 4; ++b) { cacc[a][b] = f32x4{0.f, 0.f, 0.f, 0.f}; es[a][b] = 0.f; }

  const size_t base = ((size_t)bh * Nn + chunk * 512) * Dd;

  for (int sub = 0; sub < 8; ++sub) {
    __syncthreads();  // prev sub's ctx GEMMs done (Eh/Vh/vtmp free)
    {  // stage V rows -> vtmp (coalesced)
      const int n = t >> 3, d0 = (t & 7) * 8;
      const float* vs = V + base + (size_t)(sub * 64 + n) * 64 + d0;
      *(float4*)&vtmp[n][d0] = *(const float4*)vs;
      *(float4*)&vtmp[n][d0 + 4] = *(const float4*)(vs + 4);
    }
    // K fragments (global direct) + diag via shfl
    short8v kh[2], kl[2];
    float dg4[4];
    {
      const float* ks = K + base + (size_t)(sub * 64 + rt * 16 + llo) * 64 + koff;
      float4 a0 = *(const float4*)ks;
      float4 a1 = *(const float4*)(ks + 4);
      float4 b0 = *(const float4*)(ks + 32);
      float4 b1 = *(const float4*)(ks + 36);
      float xs[16] = {a0.x, a0.y, a0.z, a0.w, a1.x, a1.y, a1.z, a1.w,
                      b0.x, b0.y, b0.z, b0.w, b1.x, b1.y, b1.z, b1.w};
      float s = 0.f;
#pragma unroll
      for (int i = 0; i < 16; ++i) s = fmaf(xs[i], xs[i], s);
      s += __shfl_xor(s, 16);
      s += __shfl_xor(s, 32);
      const float dgfull = s * kDiagCoef;  // diag of row rt*16+llo
#pragma unroll
      for (int kb = 0; kb < 2; ++kb) {
        short8v h8, l8;
#pragma unroll
        for (int i = 0; i < 8; ++i) {
          short hh, ll;
          splitbf(kNorm * xs[kb * 8 + i], hh, ll);
          h8[i] = hh; l8[i] = ll;
        }
        kh[kb] = h8; kl[kb] = l8;
      }
#pragma unroll
      for (int jj = 0; jj < 4; ++jj) dg4[jj] = __shfl(dgfull, lhi * 4 + jj);
    }

    // dd GEMM mh=0 + E store (Eh free since top-of-sub sync)
#pragma unroll
    for (int mh = 0; mh < 2; ++mh) {
      if (mh == 1) __syncthreads();  // ctx mh=0 done reading Eh
#pragma unroll
      for (int mt = 0; mt < 4; ++mt) {
        const int mloc = (msel * 4 + mt) * 16 + llo;
        const short* ph = PhG + (mh * 128 + mloc) * 64 + koff;
        const short* pl = PlG + (mh * 128 + mloc) * 64 + koff;
        f32x4 acc = f32x4{0.f, 0.f, 0.f, 0.f};
#pragma unroll
        for (int kb = 0; kb < 2; ++kb) {
          short8v pbh = *(const short8v*)(ph + kb * 32);
          short8v pbl = *(const short8v*)(pl + kb * 32);
          acc = MFMA16(kh[kb], pbh, acc);
          acc = MFMA16(kh[kb], pbl, acc);
          acc = MFMA16(kl[kb], pbh, acc);
        }
        short4v h4, l4;
        float est = 0.f;
#pragma unroll
        for (int jj = 0; jj < 4; ++jj) {
          float dd = acc[jj];
          mx = fmaxf(mx, dd);
          float E = __expf(dd - dg4[jj]);
          est += E;
          short hh, ll;
          splitbf(E, hh, ll);
          h4[jj] = hh; l4[jj] = ll;
        }
        es[mh][mt] += est;
        const int n0 = rt * 16 + lhi * 4;
        const int c = sw8(mloc, n0);
        *(short4v*)&Eh[mloc][c] = h4;
        *(short4v*)&El[mloc][c] = l4;
      }
      if (mh == 0) {
        __syncthreads();  // vtmp staged; Eh(mh0) stored
        {  // transpose V (+vsum) -> Vh/Vl
          const int e = t & 63, n0 = (t >> 6) * 8;
          short8v h8, l8;
#pragma unroll
          for (int i = 0; i < 8; ++i) {
            float xv = vtmp[n0 + i][e];
            vsum_r += xv;
            short hh, ll;
            splitbf(xv, hh, ll);
            h8[i] = hh; l8[i] = ll;
          }
          const int c = sw8(e, n0);
          *(short8v*)&Vh[e][c] = h8;
          *(short8v*)&Vl[e][c] = l8;
        }
      }
      __syncthreads();  // Eh(mh) + Vh ready
      {  // ctx GEMM for this half
        const int erow = w * 16 + llo;
        short8v eh2[2], el2[2];
#pragma unroll
        for (int kb = 0; kb < 2; ++kb) {
          const int c = sw8(erow, kb * 32 + koff);
          eh2[kb] = *(const short8v*)&Eh[erow][c];
          el2[kb] = *(const short8v*)&El[erow][c];
        }
#pragma unroll
        for (int et = 0; et < 4; ++et) {
          const int ecol = et * 16 + llo;
          f32x4 a2 = cacc[mh][et];
#pragma unroll
          for (int kb = 0; kb < 2; ++kb) {
            const int c = sw8(ecol, kb * 32 + koff);
            short8v vh2 = *(const short8v*)&Vh[ecol][c];
            short8v vl2 = *(const short8v*)&Vl[ecol][c];
            a2 = MFMA16(eh2[kb], vh2, a2);
            a2 = MFMA16(eh2[kb], vl2, a2);
            a2 = MFMA16(el2[kb], vh2, a2);
          }
          cacc[mh][et] = a2;
        }
      }
    }
  }

  // reductions
#pragma unroll
  for (int off = 32; off; off >>= 1) mx = fmaxf(mx, __shfl_xor(mx, off));
  if (l == 0) wpmax[w] = mx;
#pragma unroll
  for (int mh = 0; mh < 2; ++mh)
#pragma unroll
    for (int mt = 0; mt < 4; ++mt) {
      float v2 = es[mh][mt];
      v2 += __shfl_xor(v2, 16);
      v2 += __shfl_xor(v2, 32);
      if (l < 16) atomicAdd(&EsumG[bh * 256 + mh * 128 + (msel * 4 + mt) * 16 + l], v2);
    }
  rpartV[w][l] = vsum_r;
  __syncthreads();
  if (t < 64) {
    float s2 = 0.f;
#pragma unroll
    for (int w2 = 0; w2 < 8; ++w2) s2 += rpartV[w2][t];
    atomicAdd(&VsumG[bh * 64 + t], s2);
  }
  if (t == 0) {
    float b = wpmax[0];
#pragma unroll
    for (int w2 = 1; w2 < 8; ++w2) b = fmaxf(b, wpmax[w2]);
    atomicMax(stabKey + bh, floatKey(b));
  }
#pragma unroll
  for (int mh = 0; mh < 2; ++mh)
#pragma unroll
    for (int et = 0; et < 4; ++et)
#pragma unroll
      for (int jj = 0; jj < 4; ++jj) {
        const int m2 = mh * 128 + w * 16 + lhi * 4 + jj;
        const int e2 = et * 16 + llo;
        atomicAdd(&ctxEG[((size_t)bh * 256 + m2) * 64 + e2], cacc[mh][et][jj]);
      }
}

// ---------------------------------------------------------------------------
// combine: kshat[m] = e^{-stab}*Esum + eps*N; ctxhat -> transposed bf16 pair.
// ---------------------------------------------------------------------------
__global__ __launch_bounds__(256) void perf_combine(
    const unsigned* __restrict__ stabKey, const float* __restrict__ EsumG,
    const float* __restrict__ VsumG, const float* __restrict__ ctxEG,
    float* __restrict__ kshatG, short* __restrict__ ctHG, short* __restrict__ ctLG) {
  const int bh = blockIdx.x, t = threadIdx.x;
  const float esc = __expf(-keyToFloat(stabKey[bh]));
  kshatG[bh * 256 + t] = esc * EsumG[bh * 256 + t] + kEps * 4096.0f;
  for (int e = 0; e < 64; ++e) {
    const float v2 = esc * ctxEG[((size_t)bh * 256 + t) * 64 + e] + kEps * VsumG[bh * 64 + e];
    short hh, ll;
    splitbf(v2, hh, ll);
    ctHG[((size_t)bh * 64 + e) * 256 + t] = hh;
    ctLG[((size_t)bh * 64 + e) * 256 + t] = ll;
  }
}

// ---------------------------------------------------------------------------
// qside: grid (96, 64), block 512, 64 q-rows/block. LDS 65 KB -> 2 blocks/CU.
// dd = MFMA(a=proj frags global, b=Q frags global) -> lane holds 4 consec m
// at fixed r; rowmax/den on lane's own row; q' hi/lo -> LDS (short4 writes);
// out = MFMA(q' frags LDS, ctxhat frags global) / den.
// ---------------------------------------------------------------------------
__global__ __launch_bounds__(512, 4) void perf_qside(
    const float* __restrict__ Q, const short* __restrict__ PhG,
    const short* __restrict__ PlG, const float* __restrict__ kshatG,
    const short* __restrict__ ctHG, const short* __restrict__ ctLG,
    float* __restrict__ out) {
  const int t = threadIdx.x, bh = blockIdx.x, rb = blockIdx.y;
  const int w = t >> 6, l = t & 63;
  const int rt = w & 3, msel = w >> 2;
  const int lhi = l >> 4, llo = l & 15;
  const int koff = lhi * 8;

  __shared__ short qph[64][256], qpl[64][256];
  __shared__ unsigned rmaxKey[64];
  __shared__ float denL[64];

  if (t < 64) { rmaxKey[t] = 0u; denL[t] = 0.f; }
  __syncthreads();

  const int r = rt * 16 + llo;  // this lane's q-row (dd output col & frag row)

  // Q fragments + diag (global direct)
  short8v qh[2], ql[2];
  float dgq;
  {
    const float* qs = Q + ((size_t)bh * Nn + rb * 64 + r) * 64 + koff;
    float4 a0 = *(const float4*)qs;
    float4 a1 = *(const float4*)(qs + 4);
    float4 b0 = *(const float4*)(qs + 32);
    float4 b1 = *(const float4*)(qs + 36);
    float xs[16] = {a0.x, a0.y, a0.z, a0.w, a1.x, a1.y, a1.z, a1.w,
                    b0.x, b0.y, b0.z, b0.w, b1.x, b1.y, b1.z, b1.w};
    float s = 0.f;
#pragma unroll
    for (int i = 0; i < 16; ++i) s = fmaf(xs[i], xs[i], s);
    s += __shfl_xor(s, 16);
    s += __shfl_xor(s, 32);
    dgq = s * kDiagCoef;
#pragma unroll
    for (int kb = 0; kb < 2; ++kb) {
      short8v h8, l8;
#pragma unroll
      for (int i = 0; i < 8; ++i) {
        short hh, ll;
        splitbf(kNorm * xs[kb * 8 + i], hh, ll);
        h8[i] = hh; l8[i] = ll;
      }
      qh[kb] = h8; ql[kb] = l8;
    }
  }

  // dd GEMM: a = proj rows (m), b = Q rows (r) -> D[m][r]
  f32x4 dacc[8];
#pragma unroll
  for (int mt = 0; mt < 8; ++mt) {
    const short* ph = PhG + (msel * 128 + mt * 16 + llo) * 64 + koff;
    const short* pl = PlG + (msel * 128 + mt * 16 + llo) * 64 + koff;
    f32x4 acc = f32x4{0.f, 0.f, 0.f, 0.f};
#pragma unroll
    for (int kb = 0; kb < 2; ++kb) {
      short8v pbh = *(const short8v*)(ph + kb * 32);
      short8v pbl = *(const short8v*)(pl + kb * 32);
      acc = MFMA16(pbh, qh[kb], acc);
      acc = MFMA16(pbh, ql[kb], acc);
      acc = MFMA16(pbl, qh[kb], acc);
    }
    dacc[mt] = acc;
  }

  // rowmax over this wave's 128 m's, merged across msel pair via LDS
  {
    float mx = dacc[0][0];
#pragma unroll
    for (int mt = 0; mt < 8; ++mt)
#pragma unroll
      for (int jj = 0; jj < 4; ++jj) mx = fmaxf(mx, dacc[mt][jj]);
    mx = fmaxf(mx, __shfl_xor(mx, 16));
    mx = fmaxf(mx, __shfl_xor(mx, 32));
    if (l < 16) atomicMax(&rmaxKey[rt * 16 + l], floatKey(mx));
  }
  __syncthreads();

  // exp -> q' hi/lo (vector LDS writes), den partial
  {
    const float shift = dgq + keyToFloat(rmaxKey[r]);
    float den = 0.f;
#pragma unroll
    for (int mt = 0; mt < 8; ++mt) {
      const int m0 = msel * 128 + mt * 16 + lhi * 4;
      const f32x4 ksv = *(const f32x4*)(kshatG + bh * 256 + m0);
      short4v h4, l4;
#pragma unroll
      for (int jj = 0; jj < 4; ++jj) {
        float qv = __expf(dacc[mt][jj] - shift) + kEps;
        den = fmaf(qv, ksv[jj], den);
        short hh, ll;
        splitbf(qv, hh, ll);
        h4[jj] = hh; l4[jj] = ll;
      }
      const int c = m0 ^ ((r & 31) << 3);
      *(short4v*)&qph[r][c] = h4;
      *(short4v*)&qpl[r][c] = l4;
    }
    den += __shfl_xor(den, 16);
    den += __shfl_xor(den, 32);
    if (l < 16) atomicAdd(&denL[rt * 16 + l], den);
  }
  __syncthreads();

  // output GEMM: a = q' rows (r), b = ctxhat^T rows (e) from global
  f32x4 oacc[2] = {f32x4{0.f, 0.f, 0.f, 0.f}, f32x4{0.f, 0.f, 0.f, 0.f}};
#pragma unroll
  for (int kc = 0; kc < 8; ++kc) {
    const int mb = kc * 32 + koff;
    const int ca = mb ^ ((r & 31) << 3);
    short8v qh8 = *(const short8v*)&qph[r][ca];
    short8v ql8 = *(const short8v*)&qpl[r][ca];
#pragma unroll
    for (int et = 0; et < 2; ++et) {
      const int erow = (msel * 2 + et) * 16 + llo;
      const short* cth = ctHG + ((size_t)bh * 64 + erow) * 256 + mb;
      const short* ctl = ctLG + ((size_t)bh * 64 + erow) * 256 + mb;
      short8v th = *(const short8v*)cth;
      short8v tl = *(const short8v*)ctl;
      oacc[et] = MFMA16(qh8, th, oacc[et]);
      oacc[et] = MFMA16(qh8, tl, oacc[et]);
      oacc[et] = MFMA16(ql8, th, oacc[et]);
    }
  }

  // epilogue: divide by den, store (out rows = rt*16 + lhi*4 + jj)
  float inv[4];
#pragma unroll
  for (int jj = 0; jj < 4; ++jj) inv[jj] = 1.0f / denL[rt * 16 + lhi * 4 + jj];
#pragma unroll
  for (int et = 0; et < 2; ++et)
#pragma unroll
    for (int jj = 0; jj < 4; ++jj) {
      const int ro = rt * 16 + lhi * 4 + jj;
      const int e2 = (msel * 2 + et) * 16 + llo;
      out[((size_t)bh * Nn + rb * 64 + ro) * 64 + e2] = oacc[et][jj] * inv[jj];
    }
}

extern "C" void kernel_launch(void* const* d_in, const int* in_sizes, int n_in,
                              void* d_out, int out_size, void* d_ws, size_t ws_size,
                              hipStream_t stream) {
  const float* q = (const float*)d_in[0];
  const float* k = (const float*)d_in[1];
  const float* v = (const float*)d_in[2];
  const float* proj = (const float*)d_in[3];
  float* outp = (float*)d_out;

  char* ws = (char*)d_ws;
  unsigned* stabKey = (unsigned*)(ws + oStab);
  float* EsumG = (float*)(ws + oEsum);
  float* VsumG = (float*)(ws + oVsum);
  float* kshatG = (float*)(ws + oKshat);
  float* ctxEG = (float*)(ws + oCtxE);
  short* ctHG = (short*)(ws + oCtH);
  short* ctLG = (short*)(ws + oCtL);
  short* PhG = (short*)(ws + oPh);
  short* PlG = (short*)(ws + oPl);

  hipMemsetAsync(d_ws, 0, kZeroBytes, stream);
  perf_prep<<<16, 256, 0, stream>>>(proj, PhG, PlG);
  perf_kside<<<dim3(BHn, 8), 512, 0, stream>>>(k, v, PhG, PlG, stabKey, EsumG, VsumG, ctxEG);
  perf_combine<<<BHn, 256, 0, stream>>>(stabKey, EsumG, VsumG, ctxEG, kshatG, ctHG, ctLG);
  perf_qside<<<dim3(BHn, 64), 512, 0, stream>>>(q, PhG, PlG, kshatG, ctHG, ctLG, outp);
}

// Round 6
// 362.420 us; speedup vs baseline: 1.9519x; 1.9519x over previous
//
#include <hip/hip_runtime.h>
#include <hip/hip_bf16.h>
#include <float.h>

// Performer FastAttention (FAVOR+), MFMA bf16-split v3.
// Round 6: round-3 structure (LDS-resident operands) + pre-split proj copy-in
// + qside operand-swap (vector q' stores, lane-local rowmax/den).

typedef __attribute__((ext_vector_type(8))) short short8v;
typedef __attribute__((ext_vector_type(4))) short short4v;
typedef __attribute__((ext_vector_type(4))) float f32x4;

#define MFMA16(a, b, c) __builtin_amdgcn_mfma_f32_16x16x32_bf16(a, b, c, 0, 0, 0)

namespace {
constexpr int Nn = 4096, Dd = 64, BHn = 96;
constexpr float kNorm = 0.35355339059327379f;  // 64^-0.25
constexpr float kDiagCoef = 0.0625f;           // 0.5 * 64^-0.5
constexpr float kEps = 1e-4f;

constexpr size_t oStab  = 0;                                   // 96 u32
constexpr size_t oEsum  = 512;                                 // 96*256 f32
constexpr size_t oVsum  = oEsum + (size_t)BHn * 256 * 4;       // 96*64 f32
constexpr size_t oKshat = oVsum + (size_t)BHn * 64 * 4;        // 96*256 f32
constexpr size_t oCtxE  = oKshat + (size_t)BHn * 256 * 4;      // 96*256*64 f32
constexpr size_t oCtH   = oCtxE + (size_t)BHn * 256 * 64 * 4;  // 96*64*256 bf16
constexpr size_t oCtL   = oCtH + (size_t)BHn * 64 * 256 * 2;
constexpr size_t oPh    = oCtL + (size_t)BHn * 64 * 256 * 2;   // 256*64 bf16
constexpr size_t oPl    = oPh + (size_t)256 * 64 * 2;
constexpr size_t kZeroBytes = oCtH;  // zero stab..ctxE accumulators
}

static __device__ __forceinline__ unsigned floatKey(float f) {
  unsigned b = __float_as_uint(f);
  return (b & 0x80000000u) ? ~b : (b | 0x80000000u);
}
static __device__ __forceinline__ float keyToFloat(unsigned k) {
  unsigned b = (k & 0x80000000u) ? (k & 0x7fffffffu) : ~k;
  return __uint_as_float(b);
}
static __device__ __forceinline__ short f2bf(float x) {
  union { __hip_bfloat16 h; short s; } u;
  u.h = __float2bfloat16(x);
  return u.s;
}
static __device__ __forceinline__ float bf2f(short s) {
  return __uint_as_float(((unsigned)(unsigned short)s) << 16);
}
static __device__ __forceinline__ void splitbf(float x, short& h, short& l) {
  h = f2bf(x);
  l = f2bf(x - bf2f(h));
}
static __device__ __forceinline__ int sw8(int row, int col)  { return col ^ ((row & 7) << 3); }
static __device__ __forceinline__ int sw16(int row, int col) { return col ^ ((row & 15) << 3); }

// ---------------------------------------------------------------------------
// prep: split proj into bf16 hi/lo, linear [m][d] layout in ws.
// ---------------------------------------------------------------------------
__global__ void perf_prep(const float* __restrict__ proj, short* __restrict__ Ph,
                          short* __restrict__ Pl) {
  const int i = (blockIdx.x * 256 + threadIdx.x) * 4;  // 16384 elems
  float4 v = *(const float4*)(proj + i);
  float xs[4] = {v.x, v.y, v.z, v.w};
  short4v h, l;
#pragma unroll
  for (int j = 0; j < 4; ++j) {
    short hh, ll;
    splitbf(xs[j], hh, ll);
    h[j] = hh;
    l[j] = ll;
  }
  *(short4v*)(Ph + i) = h;
  *(short4v*)(Pl + i) = l;
}

// ---------------------------------------------------------------------------
// kside: grid (96, 16), block 512 (8 waves). 256 k-rows/block, 4 subs of 64.
// dd = (norm*k)·proj^T (split MFMA, operands LDS); E = exp(dd-diag) -> E^T LDS;
// ctxE += E^T·v; Esum/Vsum/stab accumulated. proj copy-loaded pre-split.
// ---------------------------------------------------------------------------
__global__ __launch_bounds__(512, 2) void perf_kside(
    const float* __restrict__ K, const float* __restrict__ V,
    const short* __restrict__ PhG, const short* __restrict__ PlG,
    unsigned* __restrict__ stabKey, float* __restrict__ EsumG,
    float* __restrict__ VsumG, float* __restrict__ ctxEG) {
  const int t = threadIdx.x, bh = blockIdx.x, chunk = blockIdx.y;
  const int w = t >> 6, l = t & 63;
  const int rt = w & 3, msel = w >> 2;
  const int lhi = l >> 4, llo = l & 15;
  const int koff = lhi * 8;

  __shared__ short Kh[64][64], Kl[64][64];
  __shared__ short Vh[64][64], Vl[64][64];   // V^T: [e][n]
  __shared__ float vtmp[64][68];
  __shared__ short Ph[256][64], Pl[256][64];
  __shared__ short Eh[128][64], El[128][64]; // E^T half: [m][n]
  __shared__ float diag[64];
  __shared__ float rpartV[8][64];
  __shared__ float wpmax[8];

  {  // copy-load pre-split proj (no VALU splitting)
    const int m = t >> 1, d0 = (t & 1) * 32;
    const short* gh = PhG + m * 64 + d0;
    const short* gl = PlG + m * 64 + d0;
#pragma unroll
    for (int i = 0; i < 4; ++i) {
      const int c = sw8(m, d0 + i * 8);
      *(short8v*)&Ph[m][c] = *(const short8v*)(gh + i * 8);
      *(short8v*)&Pl[m][c] = *(const short8v*)(gl + i * 8);
    }
  }

  float mx = -FLT_MAX, vsum_r = 0.f;
  f32x4 cacc[2][4];
  float es[2][4];
#pragma unroll
  for (int a = 0; a < 2; ++a)
#pragma unroll
    for (int b = 0; b < 4; ++b) { cacc[a][b] = f32x4{0.f, 0.f, 0.f, 0.f}; es[a][b] = 0.f; }

  const size_t base = ((size_t)bh * Nn + chunk * 256) * Dd;

  for (int sub = 0; sub < 4; ++sub) {
    __syncthreads();  // prev sub's consumers done
    {  // stage K (+split, +diag partial) and V->vtmp (coalesced)
      const int n = t >> 3, d0 = (t & 7) * 8;
      const float* ks = K + base + (size_t)(sub * 64 + n) * 64 + d0;
      const float4 a = *(const float4*)ks;
      const float4 b = *(const float4*)(ks + 4);
      float xs[8] = {a.x, a.y, a.z, a.w, b.x, b.y, b.z, b.w};
      float s = 0.f;
#pragma unroll
      for (int i = 0; i < 8; ++i) s = fmaf(xs[i], xs[i], s);
      s += __shfl_xor(s, 1); s += __shfl_xor(s, 2); s += __shfl_xor(s, 4);
      if ((t & 7) == 0) diag[n] = s * kDiagCoef;
      short8v h8, l8;
#pragma unroll
      for (int i = 0; i < 8; ++i) {
        short hh, ll;
        splitbf(kNorm * xs[i], hh, ll);
        h8[i] = hh; l8[i] = ll;
      }
      const int c = sw8(n, d0);
      *(short8v*)&Kh[n][c] = h8;
      *(short8v*)&Kl[n][c] = l8;
      const float* vs = V + base + (size_t)(sub * 64 + n) * 64 + d0;
      *(float4*)&vtmp[n][d0] = *(const float4*)vs;
      *(float4*)&vtmp[n][d0 + 4] = *(const float4*)(vs + 4);
    }
    __syncthreads();
    {  // transpose V (+vsum) -> Vh/Vl
      const int e = t & 63, n0 = (t >> 6) * 8;
      short8v h8, l8;
#pragma unroll
      for (int i = 0; i < 8; ++i) {
        float xv = vtmp[n0 + i][e];
        vsum_r += xv;
        short hh, ll;
        splitbf(xv, hh, ll);
        h8[i] = hh; l8[i] = ll;
      }
      const int c = sw8(e, n0);
      *(short8v*)&Vh[e][c] = h8;
      *(short8v*)&Vl[e][c] = l8;
    }
    __syncthreads();

    float dg4[4];
#pragma unroll
    for (int jj = 0; jj < 4; ++jj) dg4[jj] = diag[rt * 16 + lhi * 4 + jj];

    const int arow = rt * 16 + llo;
    short8v ah[2], al[2];
#pragma unroll
    for (int kb = 0; kb < 2; ++kb) {
      const int c = sw8(arow, kb * 32 + koff);
      ah[kb] = *(const short8v*)&Kh[arow][c];
      al[kb] = *(const short8v*)&Kl[arow][c];
    }

    for (int mh = 0; mh < 2; ++mh) {
      if (mh == 1) __syncthreads();  // ctx mh=0 done reading Eh
      // dd GEMM for this wave's 4 m-tiles of the half, exp -> E^T
#pragma unroll
      for (int mt = 0; mt < 4; ++mt) {
        const int mloc = (msel * 4 + mt) * 16 + llo;
        const int mrow = mh * 128 + mloc;
        f32x4 acc = f32x4{0.f, 0.f, 0.f, 0.f};
#pragma unroll
        for (int kb = 0; kb < 2; ++kb) {
          const int c = sw8(mrow, kb * 32 + koff);
          short8v pbh = *(const short8v*)&Ph[mrow][c];
          short8v pbl = *(const short8v*)&Pl[mrow][c];
          acc = MFMA16(ah[kb], pbh, acc);
          acc = MFMA16(ah[kb], pbl, acc);
          acc = MFMA16(al[kb], pbh, acc);
        }
        short4v h4, l4;
        float est = 0.f;
#pragma unroll
        for (int jj = 0; jj < 4; ++jj) {
          float dd = acc[jj];
          mx = fmaxf(mx, dd);
          float E = __expf(dd - dg4[jj]);
          est += E;
          short hh, ll;
          splitbf(E, hh, ll);
          h4[jj] = hh; l4[jj] = ll;
        }
        es[mh][mt] += est;
        const int n0 = rt * 16 + lhi * 4;
        const int c = sw8(mloc, n0);
        *(short4v*)&Eh[mloc][c] = h4;
        *(short4v*)&El[mloc][c] = l4;
      }
      __syncthreads();  // Eh(mh) ready
      {  // ctx GEMM for this half: wave owns m-rows w*16..+16, all 4 e-tiles
        const int erow = w * 16 + llo;
        short8v eh2[2], el2[2];
#pragma unroll
        for (int kb = 0; kb < 2; ++kb) {
          const int c = sw8(erow, kb * 32 + koff);
          eh2[kb] = *(const short8v*)&Eh[erow][c];
          el2[kb] = *(const short8v*)&El[erow][c];
        }
#pragma unroll
        for (int et = 0; et < 4; ++et) {
          const int ecol = et * 16 + llo;
          f32x4 a2 = cacc[mh][et];
#pragma unroll
          for (int kb = 0; kb < 2; ++kb) {
            const int c = sw8(ecol, kb * 32 + koff);
            short8v vh2 = *(const short8v*)&Vh[ecol][c];
            short8v vl2 = *(const short8v*)&Vl[ecol][c];
            a2 = MFMA16(eh2[kb], vh2, a2);
            a2 = MFMA16(eh2[kb], vl2, a2);
            a2 = MFMA16(el2[kb], vh2, a2);
          }
          cacc[mh][et] = a2;
        }
      }
    }
  }

  // reductions
#pragma unroll
  for (int off = 32; off; off >>= 1) mx = fmaxf(mx, __shfl_xor(mx, off));
  if (l == 0) wpmax[w] = mx;
#pragma unroll
  for (int mh = 0; mh < 2; ++mh)
#pragma unroll
    for (int mt = 0; mt < 4; ++mt) {
      float v2 = es[mh][mt];
      v2 += __shfl_xor(v2, 16);
      v2 += __shfl_xor(v2, 32);
      if (l < 16) atomicAdd(&EsumG[bh * 256 + mh * 128 + (msel * 4 + mt) * 16 + l], v2);
    }
  rpartV[w][l] = vsum_r;
  __syncthreads();
  if (t < 64) {
    float s2 = 0.f;
#pragma unroll
    for (int w2 = 0; w2 < 8; ++w2) s2 += rpartV[w2][t];
    atomicAdd(&VsumG[bh * 64 + t], s2);
  }
  if (t == 0) {
    float b = wpmax[0];
#pragma unroll
    for (int w2 = 1; w2 < 8; ++w2) b = fmaxf(b, wpmax[w2]);
    atomicMax(stabKey + bh, floatKey(b));
  }
#pragma unroll
  for (int mh = 0; mh < 2; ++mh)
#pragma unroll
    for (int et = 0; et < 4; ++et)
#pragma unroll
      for (int jj = 0; jj < 4; ++jj) {
        const int m2 = mh * 128 + w * 16 + lhi * 4 + jj;
        const int e2 = et * 16 + llo;
        atomicAdd(&ctxEG[((size_t)bh * 256 + m2) * 64 + e2], cacc[mh][et][jj]);
      }
}

// ---------------------------------------------------------------------------
// combine: kshat[m] = e^{-stab}*Esum + eps*N; ctxhat -> transposed bf16 pair.
// ---------------------------------------------------------------------------
__global__ __launch_bounds__(256) void perf_combine(
    const unsigned* __restrict__ stabKey, const float* __restrict__ EsumG,
    const float* __restrict__ VsumG, const float* __restrict__ ctxEG,
    float* __restrict__ kshatG, short* __restrict__ ctHG, short* __restrict__ ctLG) {
  const int bh = blockIdx.x, t = threadIdx.x;
  const float esc = __expf(-keyToFloat(stabKey[bh]));
  kshatG[bh * 256 + t] = esc * EsumG[bh * 256 + t] + kEps * 4096.0f;
  for (int e = 0; e < 64; ++e) {
    const float v2 = esc * ctxEG[((size_t)bh * 256 + t) * 64 + e] + kEps * VsumG[bh * 64 + e];
    short hh, ll;
    splitbf(v2, hh, ll);
    ctHG[((size_t)bh * 64 + e) * 256 + t] = hh;
    ctLG[((size_t)bh * 64 + e) * 256 + t] = ll;
  }
}

// ---------------------------------------------------------------------------
// qside: grid (96, 64), block 512, 64 q-rows/block. LDS ~130 KB, 1 blk/CU.
// dd = MFMA(A=proj from LDS, B=Q frags in regs) -> lane-local row r;
// rowmax/den lane-local; q' hi/lo vector-stored; out GEMM from LDS (ctT
// staged per half into reused Ph/Pl space).
// ---------------------------------------------------------------------------
__global__ __launch_bounds__(512, 2) void perf_qside(
    const float* __restrict__ Q, const short* __restrict__ PhG,
    const short* __restrict__ PlG, const float* __restrict__ kshatG,
    const short* __restrict__ ctHG, const short* __restrict__ ctLG,
    float* __restrict__ out) {
  const int t = threadIdx.x, bh = blockIdx.x, rb = blockIdx.y;
  const int w = t >> 6, l = t & 63;
  const int rt = w & 3, msel = w >> 2;
  const int lhi = l >> 4, llo = l & 15;
  const int koff = lhi * 8;

  __shared__ short Ph[256][64], Pl[256][64];   // reused as ctT [64][128] later
  __shared__ short qph[64][256], qpl[64][256];
  __shared__ float kshatL[256];
  __shared__ unsigned rmaxKey[64];
  __shared__ float denL[64];

  if (t < 64) { rmaxKey[t] = 0u; denL[t] = 0.f; }
  if (t < 256) kshatL[t] = kshatG[bh * 256 + t];
  {  // copy-load pre-split proj
    const int m = t >> 1, d0 = (t & 1) * 32;
    const short* gh = PhG + m * 64 + d0;
    const short* gl = PlG + m * 64 + d0;
#pragma unroll
    for (int i = 0; i < 4; ++i) {
      const int c = sw8(m, d0 + i * 8);
      *(short8v*)&Ph[m][c] = *(const short8v*)(gh + i * 8);
      *(short8v*)&Pl[m][c] = *(const short8v*)(gl + i * 8);
    }
  }

  const int r = rt * 16 + llo;  // this lane's q-row

  // Q fragments + diag (global direct, coalesced-ish; folded norm)
  short8v qh[2], ql[2];
  float dgq;
  {
    const float* qs = Q + ((size_t)bh * Nn + rb * 64 + r) * 64 + koff;
    float4 a0 = *(const float4*)qs;
    float4 a1 = *(const float4*)(qs + 4);
    float4 b0 = *(const float4*)(qs + 32);
    float4 b1 = *(const float4*)(qs + 36);
    float xs[16] = {a0.x, a0.y, a0.z, a0.w, a1.x, a1.y, a1.z, a1.w,
                    b0.x, b0.y, b0.z, b0.w, b1.x, b1.y, b1.z, b1.w};
    float s = 0.f;
#pragma unroll
    for (int i = 0; i < 16; ++i) s = fmaf(xs[i], xs[i], s);
    s += __shfl_xor(s, 16);
    s += __shfl_xor(s, 32);
    dgq = s * kDiagCoef;
#pragma unroll
    for (int kb = 0; kb < 2; ++kb) {
      short8v h8, l8;
#pragma unroll
      for (int i = 0; i < 8; ++i) {
        short hh, ll;
        splitbf(kNorm * xs[kb * 8 + i], hh, ll);
        h8[i] = hh; l8[i] = ll;
      }
      qh[kb] = h8; ql[kb] = l8;
    }
  }
  __syncthreads();  // Ph/Pl + kshatL + rmax/den init ready

  // dd GEMM: A = proj rows (LDS), B = Q frags (regs) -> D[m][r]
  f32x4 dacc[8];
#pragma unroll
  for (int mt = 0; mt < 8; ++mt) {
    const int mrow = msel * 128 + mt * 16 + llo;
    f32x4 acc = f32x4{0.f, 0.f, 0.f, 0.f};
#pragma unroll
    for (int kb = 0; kb < 2; ++kb) {
      const int c = sw8(mrow, kb * 32 + koff);
      short8v pbh = *(const short8v*)&Ph[mrow][c];
      short8v pbl = *(const short8v*)&Pl[mrow][c];
      acc = MFMA16(pbh, qh[kb], acc);
      acc = MFMA16(pbh, ql[kb], acc);
      acc = MFMA16(pbl, qh[kb], acc);
    }
    dacc[mt] = acc;
  }

  // rowmax over this wave's 128 m's, merged across msel pair via LDS
  {
    float mx = dacc[0][0];
#pragma unroll
    for (int mt = 0; mt < 8; ++mt)
#pragma unroll
      for (int jj = 0; jj < 4; ++jj) mx = fmaxf(mx, dacc[mt][jj]);
    mx = fmaxf(mx, __shfl_xor(mx, 16));
    mx = fmaxf(mx, __shfl_xor(mx, 32));
    if (l < 16) atomicMax(&rmaxKey[rt * 16 + l], floatKey(mx));
  }
  __syncthreads();  // rmax merged; all dd GEMMs done (Ph/Pl now dead)

  // exp -> q' hi/lo (vector LDS stores), den partial; stage ctT half 0
  {
    const float shift = dgq + keyToFloat(rmaxKey[r]);
    float den = 0.f;
#pragma unroll
    for (int mt = 0; mt < 8; ++mt) {
      const int m0 = msel * 128 + mt * 16 + lhi * 4;
      const f32x4 ksv = *(const f32x4*)&kshatL[m0];
      short4v h4, l4;
#pragma unroll
      for (int jj = 0; jj < 4; ++jj) {
        float qv = __expf(dacc[mt][jj] - shift) + kEps;
        den = fmaf(qv, ksv[jj], den);
        short hh, ll;
        splitbf(qv, hh, ll);
        h4[jj] = hh; l4[jj] = ll;
      }
      const int c = m0 ^ ((r & 31) << 3);
      *(short4v*)&qph[r][c] = h4;
      *(short4v*)&qpl[r][c] = l4;
    }
    den += __shfl_xor(den, 16);
    den += __shfl_xor(den, 32);
    if (l < 16) atomicAdd(&denL[rt * 16 + l], den);
  }

  // output GEMM over 2 m-halves; ctT staged into reused Ph/Pl
  short(*ctTh)[128] = (short(*)[128])Ph;
  short(*ctTl)[128] = (short(*)[128])Pl;
  f32x4 oacc[2] = {f32x4{0.f, 0.f, 0.f, 0.f}, f32x4{0.f, 0.f, 0.f, 0.f}};
#pragma unroll
  for (int mh2 = 0; mh2 < 2; ++mh2) {
    if (mh2 == 1) __syncthreads();  // prev-half MFMA done reading ctT
    {  // stage ctxhatT half (already bf16 pair in global)
      const int e = t >> 3, mg = t & 7;
      const short* gh = ctHG + ((size_t)bh * 64 + e) * 256 + mh2 * 128 + mg * 16;
      const short* gl = ctLG + ((size_t)bh * 64 + e) * 256 + mh2 * 128 + mg * 16;
      short8v a0 = *(const short8v*)gh;
      short8v a1 = *(const short8v*)(gh + 8);
      short8v b0 = *(const short8v*)gl;
      short8v b1 = *(const short8v*)(gl + 8);
      *(short8v*)&ctTh[e][sw16(e, mg * 16)] = a0;
      *(short8v*)&ctTh[e][sw16(e, mg * 16 + 8)] = a1;
      *(short8v*)&ctTl[e][sw16(e, mg * 16)] = b0;
      *(short8v*)&ctTl[e][sw16(e, mg * 16 + 8)] = b1;
    }
    __syncthreads();  // qp (mh2=0 only) + ctT ready
#pragma unroll
    for (int kb = 0; kb < 4; ++kb) {
      const int mb = mh2 * 128 + kb * 32 + koff;
      const int ca = mb ^ ((r & 31) << 3);
      short8v qh8 = *(const short8v*)&qph[r][ca];
      short8v ql8 = *(const short8v*)&qpl[r][ca];
#pragma unroll
      for (int et = 0; et < 2; ++et) {
        const int erow = (msel * 2 + et) * 16 + llo;
        const int cb = sw16(erow, kb * 32 + koff);
        short8v th = *(const short8v*)&ctTh[erow][cb];
        short8v tl = *(const short8v*)&ctTl[erow][cb];
        oacc[et] = MFMA16(qh8, th, oacc[et]);
        oacc[et] = MFMA16(qh8, tl, oacc[et]);
        oacc[et] = MFMA16(ql8, th, oacc[et]);
      }
    }
  }

  // epilogue: divide by den, store
  float inv[4];
#pragma unroll
  for (int jj = 0; jj < 4; ++jj) inv[jj] = 1.0f / denL[rt * 16 + lhi * 4 + jj];
#pragma unroll
  for (int et = 0; et < 2; ++et)
#pragma unroll
    for (int jj = 0; jj < 4; ++jj) {
      const int ro = rt * 16 + lhi * 4 + jj;
      const int e2 = (msel * 2 + et) * 16 + llo;
      out[((size_t)bh * Nn + rb * 64 + ro) * 64 + e2] = oacc[et][jj] * inv[jj];
    }
}

extern "C" void kernel_launch(void* const* d_in, const int* in_sizes, int n_in,
                              void* d_out, int out_size, void* d_ws, size_t ws_size,
                              hipStream_t stream) {
  const float* q = (const float*)d_in[0];
  const float* k = (const float*)d_in[1];
  const float* v = (const float*)d_in[2];
  const float* proj = (const float*)d_in[3];
  float* outp = (float*)d_out;

  char* ws = (char*)d_ws;
  unsigned* stabKey = (unsigned*)(ws + oStab);
  float* EsumG = (float*)(ws + oEsum);
  float* VsumG = (float*)(ws + oVsum);
  float* kshatG = (float*)(ws + oKshat);
  float* ctxEG = (float*)(ws + oCtxE);
  short* ctHG = (short*)(ws + oCtH);
  short* ctLG = (short*)(ws + oCtL);
  short* PhG = (short*)(ws + oPh);
  short* PlG = (short*)(ws + oPl);

  hipMemsetAsync(d_ws, 0, kZeroBytes, stream);
  perf_prep<<<16, 256, 0, stream>>>(proj, PhG, PlG);
  perf_kside<<<dim3(BHn, 16), 512, 0, stream>>>(k, v, PhG, PlG, stabKey, EsumG, VsumG, ctxEG);
  perf_combine<<<BHn, 256, 0, stream>>>(stabKey, EsumG, VsumG, ctxEG, kshatG, ctHG, ctLG);
  perf_qside<<<dim3(BHn, 64), 512, 0, stream>>>(q, PhG, PlG, kshatG, ctHG, ctLG, outp);
}